// Round 1
// 203.532 us; speedup vs baseline: 1.0116x; 1.0116x over previous
//
#include <hip/hip_runtime.h>
#include <hip/hip_bf16.h>

// ---- problem constants ----
#define T_TOK 2048
#define HID   1024
#define FF    1024
#define NEXP  8
#define NPAIR 4096

// ---- GEMM tiling ----
#define BM 128
#define BK 32
#define MAX_MT 40
#define MAXROWS (MAX_MT*BM)   // 5120
#define PPT (NPAIR/256)       // 16

using bf16x8 = __attribute__((ext_vector_type(8))) __bf16;
using f32x4  = __attribute__((ext_vector_type(4))) float;

__device__ __forceinline__ unsigned short f2bf(float f) {
    unsigned int u = __float_as_uint(f);
    return (unsigned short)((u + 0x7FFF + ((u >> 16) & 1)) >> 16);   // RNE
}
__device__ __forceinline__ float bf2f(unsigned short s) {
    return __uint_as_float(((unsigned int)s) << 16);
}
__device__ __forceinline__ void gll16(const unsigned short* g, unsigned short* l) {
    __builtin_amdgcn_global_load_lds(
        (const __attribute__((address_space(1))) void*)(const void*)g,
        (__attribute__((address_space(3))) void*)(void*)l, 16, 0, 0);
}

// ---------------- prep (blocks 0..2047) + setup (block 2048) ----------------
__global__ void prep_kernel(const float* __restrict__ wgu,
                            const float* __restrict__ wdn,
                            const float* __restrict__ hs,
                            const int* __restrict__ ids,
                            int* __restrict__ pair_pos,
                            int* __restrict__ row_tok,
                            int* __restrict__ meta,
                            unsigned short* __restrict__ wgu_b,
                            unsigned short* __restrict__ wdn_b,
                            unsigned short* __restrict__ hs_b) {
    int tid = threadIdx.x;
    if (blockIdx.x == 2048) {
        // ---- setup: bucket pairs by expert via prefix scan (no atomics) ----
        __shared__ int S[2][256][NEXP];
        __shared__ int base[NEXP];
        int myc[NEXP];
        int eloc[PPT];
#pragma unroll
        for (int e = 0; e < NEXP; e++) myc[e] = 0;
#pragma unroll
        for (int i = 0; i < PPT; i++) {
            int e = ids[tid * PPT + i];
            eloc[i] = e;
#pragma unroll
            for (int ee = 0; ee < NEXP; ee++) myc[ee] += (e == ee);
        }
#pragma unroll
        for (int e = 0; e < NEXP; e++) S[0][tid][e] = myc[e];
        __syncthreads();
        int src = 0;
        for (int d = 1; d < 256; d <<= 1) {
#pragma unroll
            for (int e = 0; e < NEXP; e++) {
                int v = S[src][tid][e];
                if (tid >= d) v += S[src][tid - d][e];
                S[src ^ 1][tid][e] = v;
            }
            __syncthreads();
            src ^= 1;
        }
        if (tid == 0) {
            int mt = 0;
            for (int e = 0; e < NEXP; e++) {
                meta[e] = mt;
                base[e] = mt * BM;
                mt += (S[src][255][e] + BM - 1) / BM;
            }
            meta[NEXP] = mt;
        }
        for (int i = tid; i < MAXROWS; i += 256) row_tok[i] = -1;
        __syncthreads();
        int off[NEXP];
#pragma unroll
        for (int e = 0; e < NEXP; e++) off[e] = base[e] + S[src][tid][e] - myc[e];
#pragma unroll
        for (int i = 0; i < PPT; i++) {
            int p = tid * PPT + i;
            int e = eloc[i];
            int pos = 0;
#pragma unroll
            for (int ee = 0; ee < NEXP; ee++) if (e == ee) pos = off[ee]++;
            pair_pos[p] = pos;
            row_tok[pos] = p >> 1;
        }
        return;
    }
    // ---- flat fp32 -> bf16 conversions ----
    long stride = 2048L * 256;
    long t0 = (long)blockIdx.x * 256 + tid;
    const long NW1 = (long)NEXP * 2 * FF * HID / 4;
    for (long i = t0; i < NW1; i += stride) {
        float4 v = ((const float4*)wgu)[i];
        ushort4 o; o.x = f2bf(v.x); o.y = f2bf(v.y); o.z = f2bf(v.z); o.w = f2bf(v.w);
        ((ushort4*)wgu_b)[i] = o;
    }
    const long NW2 = (long)NEXP * HID * FF / 4;
    for (long i = t0; i < NW2; i += stride) {
        float4 v = ((const float4*)wdn)[i];
        ushort4 o; o.x = f2bf(v.x); o.y = f2bf(v.y); o.z = f2bf(v.z); o.w = f2bf(v.w);
        ((ushort4*)wdn_b)[i] = o;
    }
    const long NH = (long)T_TOK * HID / 4;
    for (long i = t0; i < NH; i += stride) {
        float4 v = ((const float4*)hs)[i];
        ushort4 o; o.x = f2bf(v.x); o.y = f2bf(v.y); o.z = f2bf(v.z); o.w = f2bf(v.w);
        ((ushort4*)hs_b)[i] = o;
    }
}

// ---------------- grouped GEMM, XCD-swizzled 1-D grid, prefetch dbuf ----------------
// EPI==1: A rows indirect via row_tok (clamped) into hs_b; B = wgu_b with gate/up
//         de-interleave in staging; epilogue silu(gate)*up -> bf16 act (FF cols).
// EPI==2: A = act (bucket-ordered, direct); epilogue plain bf16 store to ybuf.
// BN=128: each of 4 waves (2x2) computes a 64x64 sub-tile -> 16 MFMA per K-step
// per wave (2x the old BN=64), same staging/barrier overhead per K-step.
template<int EPI, int NBY, int BN>
__global__ __launch_bounds__(256)
void gemm_moe(const unsigned short* __restrict__ A,
              const unsigned short* __restrict__ B,
              unsigned short* __restrict__ Cbf,
              const int* __restrict__ meta,
              const int* __restrict__ row_tok,
              int K, long Bexp) {
    constexpr int NJ = BN / 32;                    // 16-col MFMA tiles per wave
    constexpr int NBCH = (BN * BK) / (8 * 256);    // B 16B-chunks per thread
    __shared__ unsigned short As[2][BM * BK];      // 16 KB
    __shared__ unsigned short Bs[2][BN * BK];      // 16 KB @ BN=128

    // XCD-locality decode: xcd = L%8 gets NBY/8 consecutive by-slabs for ALL bx
    int L = blockIdx.x;
    int xcd = L & 7;
    int slot = L >> 3;
    constexpr int PER = NBY / 8;
    int by = xcd * PER + (slot % PER);
    int bx = slot / PER;
    if (bx >= meta[NEXP]) return;
    int e = 0;
#pragma unroll
    for (int i = 1; i < NEXP; i++) if (bx >= meta[i]) e = i;

    long m0 = (long)bx * BM;
    int n0 = by * BN;
    const unsigned short* Bb = B + (long)e * Bexp;

    int tid = threadIdx.x, lane = tid & 63, wv = tid >> 6;
    const int r = lane & 15;
    const int q = lane >> 4;
    const int mw = (wv >> 1) * 64, nw = (wv & 1) * (BN / 2);
    const int sw = (q ^ ((r >> 1) & 3)) * 8;

    // per-thread staging pointers (rows fixed across K)
    const unsigned short* ap[2];
#pragma unroll
    for (int h = 0; h < 2; h++) {
        int c = h * 256 + tid;
        int row = c >> 2, cp = c & 3;
        int cc = cp ^ ((row >> 1) & 3);
        long grow;
        if (EPI == 1) {
            int tk = row_tok[m0 + row];
            if (tk < 0) tk = 0;               // pad rows: finite garbage, never read
            grow = tk;
        } else {
            grow = m0 + row;
        }
        ap[h] = A + grow * (long)K + cc * 8;
    }
    const unsigned short* bp[NBCH];
#pragma unroll
    for (int h = 0; h < NBCH; h++) {
        int c = h * 256 + tid;
        int row = c >> 2, cp = c & 3;
        int cc = cp ^ ((row >> 1) & 3);
        long grow;
        if (EPI == 1) grow = ((row & 1) ? FF : 0) + ((n0 + row) >> 1);
        else          grow = n0 + row;
        bp[h] = Bb + grow * (long)K + cc * 8;
    }

    auto stage = [&](int s, int k0) {
#pragma unroll
        for (int h = 0; h < 2; h++)
            gll16(ap[h] + k0, &As[s][(h * 256 + tid) * 8]);
#pragma unroll
        for (int h = 0; h < NBCH; h++)
            gll16(bp[h] + k0, &Bs[s][(h * 256 + tid) * 8]);
    };

    f32x4 acc[4][NJ] = {};
    const int NKI = K / BK;   // 32
    stage(0, 0);
    for (int ki = 0; ki < NKI; ki++) {
        __syncthreads();      // buf[ki&1] loads landed; buf[(ki+1)&1] free to overwrite
        if (ki + 1 < NKI) stage((ki + 1) & 1, (ki + 1) * BK);
        int s = ki & 1;
        bf16x8 a[4], b[NJ];
#pragma unroll
        for (int i = 0; i < 4; i++)
            a[i] = *(const bf16x8*)&As[s][(mw + i * 16 + r) * BK + sw];
#pragma unroll
        for (int j = 0; j < NJ; j++)
            b[j] = *(const bf16x8*)&Bs[s][(nw + j * 16 + r) * BK + sw];
#pragma unroll
        for (int i = 0; i < 4; i++)
#pragma unroll
            for (int j = 0; j < NJ; j++)
                acc[i][j] = __builtin_amdgcn_mfma_f32_16x16x32_bf16(a[i], b[j], acc[i][j], 0, 0, 0);
        __syncthreads();      // all reads of buf[s] done before next overwrite cycle
    }

    // D layout: row = q*4 + reg, col = lane&15 within each 16x16 tile
    if (EPI == 1) {
#pragma unroll
        for (int i = 0; i < 4; i++) {
            long rowb = m0 + mw + i * 16 + q * 4;
#pragma unroll
            for (int j = 0; j < NJ; j++) {
                int n = n0 + nw + j * 16 + r;
#pragma unroll
                for (int reg = 0; reg < 4; reg++) {
                    float v = acc[i][j][reg];
                    float o = __shfl_xor(v, 1);
                    if (!(r & 1)) {
                        float g = v, u = o;
                        float s2 = g / (1.f + __expf(-g)) * u;
                        Cbf[(rowb + reg) * (long)FF + (n >> 1)] = f2bf(s2);
                    }
                }
            }
        }
    } else {
#pragma unroll
        for (int i = 0; i < 4; i++) {
            long rowb = m0 + mw + i * 16 + q * 4;
#pragma unroll
            for (int j = 0; j < NJ; j++) {
                int n = n0 + nw + j * 16 + r;
#pragma unroll
                for (int reg = 0; reg < 4; reg++)
                    Cbf[(rowb + reg) * (long)HID + n] = f2bf(acc[i][j][reg]);
            }
        }
    }
}

// ---------------- weighted combine ----------------
__global__ void combine_kernel(const unsigned short* __restrict__ y,
                               const float* __restrict__ tw,
                               const int* __restrict__ pair_pos,
                               float* __restrict__ out) {
    int t = blockIdx.x;
    int c = threadIdx.x * 4;
    int p0 = pair_pos[t * 2], p1 = pair_pos[t * 2 + 1];
    float w0 = tw[t * 2], w1 = tw[t * 2 + 1];
    ushort4 a = *(const ushort4*)(y + (long)p0 * HID + c);
    ushort4 b = *(const ushort4*)(y + (long)p1 * HID + c);
    float4 o;
    o.x = w0 * bf2f(a.x) + w1 * bf2f(b.x);
    o.y = w0 * bf2f(a.y) + w1 * bf2f(b.y);
    o.z = w0 * bf2f(a.z) + w1 * bf2f(b.z);
    o.w = w0 * bf2f(a.w) + w1 * bf2f(b.w);
    *(float4*)(out + (long)t * HID + c) = o;
}

extern "C" void kernel_launch(void* const* d_in, const int* in_sizes, int n_in,
                              void* d_out, int out_size, void* d_ws, size_t ws_size,
                              hipStream_t stream) {
    const float* hs  = (const float*)d_in[0];
    const float* tw  = (const float*)d_in[1];
    const int*   ids = (const int*)d_in[2];
    const float* wgu = (const float*)d_in[3];
    const float* wdn = (const float*)d_in[4];
    float* out = (float*)d_out;

    char* ws = (char*)d_ws;
    size_t off = 0;
    auto alloc = [&](size_t bytes) -> void* {
        void* p = ws + off;
        off += (bytes + 255) & ~(size_t)255;
        return p;
    };
    unsigned short* wgu_b = (unsigned short*)alloc((size_t)NEXP * 2 * FF * HID * 2); // 32 MB
    unsigned short* wdn_b = (unsigned short*)alloc((size_t)NEXP * HID * FF * 2);     // 16 MB
    unsigned short* hs_b  = (unsigned short*)alloc((size_t)T_TOK * HID * 2);         // 4 MB
    unsigned short* act   = (unsigned short*)alloc((size_t)MAXROWS * FF * 2);        // 10 MB
    unsigned short* ybuf  = (unsigned short*)alloc((size_t)MAXROWS * HID * 2);       // 10 MB
    int* pair_pos = (int*)alloc(NPAIR * 4);
    int* row_tok  = (int*)alloc(MAXROWS * 4);
    int* meta     = (int*)alloc(64);

    prep_kernel<<<2049, 256, 0, stream>>>(wgu, wdn, hs, ids,
                                          pair_pos, row_tok, meta,
                                          wgu_b, wdn_b, hs_b);

    // GEMM1: (rows x 1024) x B_e(2048 x 1024)^T -> fused silu -> act (rows x 1024)
    gemm_moe<1, 16, 128><<<16 * MAX_MT, 256, 0, stream>>>(
        hs_b, wgu_b, act, meta, row_tok, HID, (long)(2 * FF) * HID);

    // GEMM2: (rows x 1024) x B_e(1024 x 1024)^T -> ybuf (rows x 1024) bf16
    gemm_moe<2, 8, 128><<<8 * MAX_MT, 256, 0, stream>>>(
        act, wdn_b, ybuf, meta, row_tok, FF, (long)HID * FF);

    combine_kernel<<<T_TOK, 256, 0, stream>>>(ybuf, tw, pair_pos, out);
}